// Round 1
// baseline (4174.289 us; speedup 1.0000x reference)
//
#include <hip/hip_runtime.h>

// LSTMPricePredictor: B=4096, T=512, IN=1, H=50, 2 layers + FC(50->1)
// Persistent kernel: 256 blocks (1 per CU) x 512 threads (8 waves).
// Each block owns TB=16 batch rows for all T=512 steps.
// Gate threads: wave w, lane<50 -> gate g = 50*(w%4)+lane, batch-half w/4.
//   Weight rows live in VGPRs (loaded once). h-state lives in LDS and is read
//   with wave-uniform (broadcast) float4 loads.
// Elementwise threads: wave w, lane<50 -> (b=2w,2w+1, k=lane), c-state in regs.

#define T_STEPS 512
#define HID 50
#define NG 200        // 4*H
#define TB 16         // batch rows per block
#define PITCH0 52     // h0 row pitch (16B-aligned rows, zero-padded)
#define PITCH1 104    // [h0_t ; h1_{t-1}] row pitch
#define GPITCH 200    // gates row pitch

__device__ __forceinline__ float sigm(float x) {
    return 1.0f / (1.0f + __expf(-x));
}
__device__ __forceinline__ float tanhh(float x) {
    // tanh(x) = 1 - 2/(exp(2x)+1); saturates correctly for |x| large
    return 1.0f - 2.0f / (1.0f + __expf(2.0f * x));
}

extern "C" __global__ __launch_bounds__(512, 2)
void lstm2_fc_kernel(const float* __restrict__ x,
                     const float* __restrict__ W_ih0, const float* __restrict__ W_hh0,
                     const float* __restrict__ b_ih0, const float* __restrict__ b_hh0,
                     const float* __restrict__ W_ih1, const float* __restrict__ W_hh1,
                     const float* __restrict__ b_ih1, const float* __restrict__ b_hh1,
                     const float* __restrict__ fc_w, const float* __restrict__ fc_b,
                     float* __restrict__ out)
{
    __shared__ float h0s[TB * PITCH0];   // layer0 hidden state h0_{t-1} (padded cols zero)
    __shared__ float hc1[TB * PITCH1];   // cols 0..49: h0_t (layer1 input), 50..99: h1_{t-1}
    __shared__ float gates[TB * GPITCH]; // gate pre-activations (reused for both layers)
    __shared__ float xt[TB];             // x[b, t] for current step

    const int tid  = threadIdx.x;
    const int lane = tid & 63;
    const int w    = tid >> 6;          // wave id 0..7
    const int b0   = blockIdx.x * TB;

    // ---- zero-init LDS state (incl. pad columns; pads stay zero forever) ----
    for (int i = tid; i < TB * PITCH0; i += 512) h0s[i] = 0.0f;
    for (int i = tid; i < TB * PITCH1; i += 512) hc1[i] = 0.0f;
    if (tid < TB) xt[tid] = x[(b0 + tid) * T_STEPS];   // t = 0 (IN == 1)

    // ---- gate-thread setup: weight rows into registers (once) ----
    const bool is_gate = (lane < HID);
    const int  g  = 50 * (w & 3) + lane;   // gate row 0..199 (valid when is_gate)
    const int  bh = w >> 2;                // batch half: 0 or 1

    float W0row[PITCH0];   // W_hh0[g, 0..49], zero pad to 52
    float W1row[PITCH1];   // [W_ih1[g,:] | W_hh1[g,:]], zero pad to 104
    float wih0 = 0.0f, bs0 = 0.0f, bs1 = 0.0f;

    #pragma unroll
    for (int j = 0; j < PITCH0; ++j) W0row[j] = 0.0f;
    #pragma unroll
    for (int j = 0; j < PITCH1; ++j) W1row[j] = 0.0f;

    if (is_gate) {
        wih0 = W_ih0[g];                       // (4H, 1)
        bs0  = b_ih0[g] + b_hh0[g];
        bs1  = b_ih1[g] + b_hh1[g];
        for (int j = 0; j < HID; ++j) {
            W0row[j]       = W_hh0[g * HID + j];
            W1row[j]       = W_ih1[g * HID + j];
            W1row[HID + j] = W_hh1[g * HID + j];
        }
    }

    // ---- elementwise-thread state: c for (b = 2w + {0,1}, k = lane) ----
    float c0r[2] = {0.0f, 0.0f};
    float c1r[2] = {0.0f, 0.0f};

    __syncthreads();

    for (int t = 0; t < T_STEPS; ++t) {
        // ---------- Phase A: layer-0 gates ----------
        if (is_gate) {
            #pragma unroll
            for (int bb = 0; bb < 8; ++bb) {
                const int b = 8 * bh + bb;
                float acc = bs0 + wih0 * xt[b];
                const float4* h4 = (const float4*)(&h0s[b * PITCH0]);
                #pragma unroll
                for (int jc = 0; jc < PITCH0 / 4; ++jc) {
                    float4 hv = h4[jc];
                    acc += W0row[4*jc+0] * hv.x + W0row[4*jc+1] * hv.y
                         + W0row[4*jc+2] * hv.z + W0row[4*jc+3] * hv.w;
                }
                gates[b * GPITCH + g] = acc;
            }
        }
        __syncthreads();

        // ---------- Phase B: layer-0 elementwise (+ prefetch x for t+1) ----------
        if (lane < HID) {
            #pragma unroll
            for (int bi = 0; bi < 2; ++bi) {
                const int b = 2 * w + bi;
                const float gi = gates[b * GPITCH + lane];
                const float gf = gates[b * GPITCH + 50 + lane];
                const float gc = gates[b * GPITCH + 100 + lane];
                const float go = gates[b * GPITCH + 150 + lane];
                const float i_ = sigm(gi);
                const float f_ = sigm(gf);
                const float c_ = tanhh(gc);
                const float o_ = sigm(go);
                const float cn = f_ * c0r[bi] + i_ * c_;
                c0r[bi] = cn;
                const float hn = o_ * tanhh(cn);
                h0s[b * PITCH0 + lane] = hn;   // for next step's layer-0 recurrence
                hc1[b * PITCH1 + lane] = hn;   // layer-1 input (this step)
            }
        } else if (w < 2) {
            const int idx = 14 * w + (lane - HID);   // 0..13 / 14..27
            if (idx < TB && (t + 1) < T_STEPS)
                xt[idx] = x[(b0 + idx) * T_STEPS + t + 1];
        }
        __syncthreads();

        // ---------- Phase C: layer-1 gates (input = [h0_t ; h1_{t-1}]) ----------
        if (is_gate) {
            #pragma unroll
            for (int bb = 0; bb < 8; ++bb) {
                const int b = 8 * bh + bb;
                float acc = bs1;
                const float4* h4 = (const float4*)(&hc1[b * PITCH1]);
                #pragma unroll
                for (int jc = 0; jc < PITCH1 / 4; ++jc) {
                    float4 hv = h4[jc];
                    acc += W1row[4*jc+0] * hv.x + W1row[4*jc+1] * hv.y
                         + W1row[4*jc+2] * hv.z + W1row[4*jc+3] * hv.w;
                }
                gates[b * GPITCH + g] = acc;
            }
        }
        __syncthreads();

        // ---------- Phase D: layer-1 elementwise ----------
        if (lane < HID) {
            #pragma unroll
            for (int bi = 0; bi < 2; ++bi) {
                const int b = 2 * w + bi;
                const float gi = gates[b * GPITCH + lane];
                const float gf = gates[b * GPITCH + 50 + lane];
                const float gc = gates[b * GPITCH + 100 + lane];
                const float go = gates[b * GPITCH + 150 + lane];
                const float i_ = sigm(gi);
                const float f_ = sigm(gf);
                const float c_ = tanhh(gc);
                const float o_ = sigm(go);
                const float cn = f_ * c1r[bi] + i_ * c_;
                c1r[bi] = cn;
                const float hn = o_ * tanhh(cn);
                hc1[b * PITCH1 + 50 + lane] = hn;   // h1_t -> next step's recurrence
            }
        }
        __syncthreads();
    }

    // ---------- Final FC: out[b] = fc_b + fc_w . h1_{T-1}[b, :] ----------
    if (tid < TB) {
        const int b = tid;
        float s = fc_b[0];
        for (int k = 0; k < HID; ++k)
            s += fc_w[k] * hc1[b * PITCH1 + 50 + k];
        out[b0 + b] = s;
    }
}

extern "C" void kernel_launch(void* const* d_in, const int* in_sizes, int n_in,
                              void* d_out, int out_size, void* d_ws, size_t ws_size,
                              hipStream_t stream) {
    (void)in_sizes; (void)n_in; (void)d_ws; (void)ws_size; (void)out_size;
    const float* x     = (const float*)d_in[0];
    const float* W_ih0 = (const float*)d_in[1];
    const float* W_hh0 = (const float*)d_in[2];
    const float* b_ih0 = (const float*)d_in[3];
    const float* b_hh0 = (const float*)d_in[4];
    const float* W_ih1 = (const float*)d_in[5];
    const float* W_hh1 = (const float*)d_in[6];
    const float* b_ih1 = (const float*)d_in[7];
    const float* b_hh1 = (const float*)d_in[8];
    const float* fc_w  = (const float*)d_in[9];
    const float* fc_b  = (const float*)d_in[10];

    dim3 grid(4096 / TB);   // 256 blocks, 1 per CU
    dim3 block(512);        // 8 waves
    lstm2_fc_kernel<<<grid, block, 0, stream>>>(
        x, W_ih0, W_hh0, b_ih0, b_hh0,
        W_ih1, W_hh1, b_ih1, b_hh1,
        fc_w, fc_b, (float*)d_out);
}

// Round 2
// 4011.027 us; speedup vs baseline: 1.0407x; 1.0407x over previous
//
#include <hip/hip_runtime.h>

// LSTMPricePredictor: B=4096, T=512, IN=1, H=50, 2 layers + FC(50->1)
// Persistent kernel: 256 blocks (1 per CU) x 512 threads (8 waves).
// Each block owns TB=16 batch rows for all T=512 steps.
// Gate threads: wave w, lane -> gate g = 50*(w%4)+min(lane,49), batch-half w/4.
//   Weight rows live in VGPRs (loaded ONCE, unconditionally, fully-unrolled
//   loops so SROA promotes the arrays -- R1 spilled them at VGPR_Count=112).
// h-state lives in LDS, read with wave-uniform (broadcast) float4 loads.
// x tile (16x512 = 32 KB) staged in LDS once at kernel start.

#define T_STEPS 512
#define HID 50
#define NG 200        // 4*H
#define TB 16         // batch rows per block
#define PITCH0 52     // h0 row pitch (16B-aligned rows, zero-padded)
#define PITCH1 104    // [h0_t ; h1_{t-1}] row pitch, cols 100..103 zero
#define GPITCH 200    // gates row pitch

__device__ __forceinline__ float sigm(float x) {
    return 1.0f / (1.0f + __expf(-x));
}
__device__ __forceinline__ float tanhh(float x) {
    return 1.0f - 2.0f / (1.0f + __expf(2.0f * x));
}

extern "C" __global__ __launch_bounds__(512, 2)
void lstm2_fc_kernel(const float* __restrict__ x,
                     const float* __restrict__ W_ih0, const float* __restrict__ W_hh0,
                     const float* __restrict__ b_ih0, const float* __restrict__ b_hh0,
                     const float* __restrict__ W_ih1, const float* __restrict__ W_hh1,
                     const float* __restrict__ b_ih1, const float* __restrict__ b_hh1,
                     const float* __restrict__ fc_w, const float* __restrict__ fc_b,
                     float* __restrict__ out)
{
    __shared__ float xs[TB * T_STEPS];   // staged x tile: xs[b][t], contiguous
    __shared__ float h0s[TB * PITCH0];   // layer0 hidden h0_{t-1} (pad cols zero)
    __shared__ float hc1[TB * PITCH1];   // cols 0..49: h0_t, 50..99: h1_{t-1}
    __shared__ float gates[TB * GPITCH]; // gate pre-activations (both layers)

    const int tid  = threadIdx.x;
    const int lane = tid & 63;
    const int w    = tid >> 6;          // wave id 0..7
    const int b0   = blockIdx.x * TB;

    // ---- stage x tile: rows b0..b0+15 are contiguous in x ----
    {
        const float4* xsrc4 = (const float4*)(x + b0 * T_STEPS);
        float4* xdst4 = (float4*)xs;
        #pragma unroll
        for (int k = 0; k < (TB * T_STEPS / 4) / 512; ++k)
            xdst4[tid + k * 512] = xsrc4[tid + k * 512];
    }

    // ---- zero-init LDS state (incl. pad columns; pads stay zero forever) ----
    for (int i = tid; i < TB * PITCH0; i += 512) h0s[i] = 0.0f;
    for (int i = tid; i < TB * PITCH1; i += 512) hc1[i] = 0.0f;

    // ---- gate-thread setup: weight rows into registers (once) ----
    const bool is_gate = (lane < HID);
    const int  g    = 50 * (w & 3) + (is_gate ? lane : 49);  // clamped, always valid
    const int  bh   = w >> 2;                                // batch half: 0 or 1

    float W0row[PITCH0];   // W_hh0[g, 0..49], zero pad to 52
    float W1row[PITCH1];   // [W_ih1[g,:] | W_hh1[g,:]], zero pad to 104

    // Unconditional, fully-unrolled loads -> SROA can promote to VGPRs.
    #pragma unroll
    for (int j = 0; j < HID; ++j) {
        W0row[j]       = W_hh0[g * HID + j];
        W1row[j]       = W_ih1[g * HID + j];
        W1row[HID + j] = W_hh1[g * HID + j];
    }
    #pragma unroll
    for (int j = HID; j < PITCH0; ++j) W0row[j] = 0.0f;
    #pragma unroll
    for (int j = 2 * HID; j < PITCH1; ++j) W1row[j] = 0.0f;

    const float wih0 = W_ih0[g];
    const float bs0  = b_ih0[g] + b_hh0[g];
    const float bs1  = b_ih1[g] + b_hh1[g];

    // ---- elementwise-thread state: c for (b = 2w + {0,1}, k = lane) ----
    float c0r[2] = {0.0f, 0.0f};
    float c1r[2] = {0.0f, 0.0f};

    __syncthreads();

    for (int t = 0; t < T_STEPS; ++t) {
        // ---------- Phase A: layer-0 gates ----------
        {
            float acc[8];
            #pragma unroll
            for (int bb = 0; bb < 8; ++bb) {
                const int b = 8 * bh + bb;
                acc[bb] = bs0 + wih0 * xs[b * T_STEPS + t];
            }
            #pragma unroll
            for (int jc = 0; jc < PITCH0 / 4; ++jc) {
                #pragma unroll
                for (int bb = 0; bb < 8; ++bb) {
                    const int b = 8 * bh + bb;
                    float4 hv = *(const float4*)(&h0s[b * PITCH0 + 4 * jc]);
                    acc[bb] += W0row[4*jc+0] * hv.x + W0row[4*jc+1] * hv.y
                             + W0row[4*jc+2] * hv.z + W0row[4*jc+3] * hv.w;
                }
            }
            if (is_gate) {
                #pragma unroll
                for (int bb = 0; bb < 8; ++bb)
                    gates[(8 * bh + bb) * GPITCH + g] = acc[bb];
            }
        }
        __syncthreads();

        // ---------- Phase B: layer-0 elementwise ----------
        if (is_gate) {
            #pragma unroll
            for (int bi = 0; bi < 2; ++bi) {
                const int b = 2 * w + bi;
                const float gi = gates[b * GPITCH + lane];
                const float gf = gates[b * GPITCH + 50 + lane];
                const float gc = gates[b * GPITCH + 100 + lane];
                const float go = gates[b * GPITCH + 150 + lane];
                const float i_ = sigm(gi);
                const float f_ = sigm(gf);
                const float c_ = tanhh(gc);
                const float o_ = sigm(go);
                const float cn = f_ * c0r[bi] + i_ * c_;
                c0r[bi] = cn;
                const float hn = o_ * tanhh(cn);
                h0s[b * PITCH0 + lane] = hn;   // next step's layer-0 recurrence
                hc1[b * PITCH1 + lane] = hn;   // layer-1 input (this step)
            }
        }
        __syncthreads();

        // ---------- Phase C: layer-1 gates (input = [h0_t ; h1_{t-1}]) ----------
        {
            float acc[8];
            #pragma unroll
            for (int bb = 0; bb < 8; ++bb) acc[bb] = bs1;
            #pragma unroll
            for (int jc = 0; jc < PITCH1 / 4; ++jc) {
                #pragma unroll
                for (int bb = 0; bb < 8; ++bb) {
                    const int b = 8 * bh + bb;
                    float4 hv = *(const float4*)(&hc1[b * PITCH1 + 4 * jc]);
                    acc[bb] += W1row[4*jc+0] * hv.x + W1row[4*jc+1] * hv.y
                             + W1row[4*jc+2] * hv.z + W1row[4*jc+3] * hv.w;
                }
            }
            if (is_gate) {
                #pragma unroll
                for (int bb = 0; bb < 8; ++bb)
                    gates[(8 * bh + bb) * GPITCH + g] = acc[bb];
            }
        }
        __syncthreads();

        // ---------- Phase D: layer-1 elementwise ----------
        if (is_gate) {
            #pragma unroll
            for (int bi = 0; bi < 2; ++bi) {
                const int b = 2 * w + bi;
                const float gi = gates[b * GPITCH + lane];
                const float gf = gates[b * GPITCH + 50 + lane];
                const float gc = gates[b * GPITCH + 100 + lane];
                const float go = gates[b * GPITCH + 150 + lane];
                const float i_ = sigm(gi);
                const float f_ = sigm(gf);
                const float c_ = tanhh(gc);
                const float o_ = sigm(go);
                const float cn = f_ * c1r[bi] + i_ * c_;
                c1r[bi] = cn;
                const float hn = o_ * tanhh(cn);
                hc1[b * PITCH1 + 50 + lane] = hn;   // h1_t -> next step
            }
        }
        __syncthreads();
    }

    // ---------- Final FC: out[b] = fc_b + fc_w . h1_{T-1}[b, :] ----------
    if (tid < TB) {
        const int b = tid;
        float s = fc_b[0];
        for (int k = 0; k < HID; ++k)
            s += fc_w[k] * hc1[b * PITCH1 + 50 + k];
        out[b0 + b] = s;
    }
}

extern "C" void kernel_launch(void* const* d_in, const int* in_sizes, int n_in,
                              void* d_out, int out_size, void* d_ws, size_t ws_size,
                              hipStream_t stream) {
    (void)in_sizes; (void)n_in; (void)d_ws; (void)ws_size; (void)out_size;
    const float* x     = (const float*)d_in[0];
    const float* W_ih0 = (const float*)d_in[1];
    const float* W_hh0 = (const float*)d_in[2];
    const float* b_ih0 = (const float*)d_in[3];
    const float* b_hh0 = (const float*)d_in[4];
    const float* W_ih1 = (const float*)d_in[5];
    const float* W_hh1 = (const float*)d_in[6];
    const float* b_ih1 = (const float*)d_in[7];
    const float* b_hh1 = (const float*)d_in[8];
    const float* fc_w  = (const float*)d_in[9];
    const float* fc_b  = (const float*)d_in[10];

    dim3 grid(4096 / TB);   // 256 blocks, 1 per CU
    dim3 block(512);        // 8 waves
    lstm2_fc_kernel<<<grid, block, 0, stream>>>(
        x, W_ih0, W_hh0, b_ih0, b_hh0,
        W_ih1, W_hh1, b_ih1, b_hh1,
        fc_w, fc_b, (float*)d_out);
}